// Round 3
// baseline (316.017 us; speedup 1.0000x reference)
//
#include <hip/hip_runtime.h>

#define NBINS 15
#define NCLS  100
#define NSEG  (NBINS * NCLS)   // 1500
#define NBLK  2048             // 8 blocks/CU
#define BLK   256
#define SUMSCALE 2048.0f       // fixed-point scale for packed sum (20-bit field)
#define INV15 (1.0f / 15.0f)   // f32 edge arithmetic (round-2/5 proven vs np)

// native clang vector type — __builtin_nontemporal_load requires this
// (HIP_vector_type<float,4> is a class and is rejected).
typedef float nf4 __attribute__((ext_vector_type(4)));

// Per-float4 bin/accumulate. Exact searchsorted-right semantics preserved
// from the verified kernel: k = largest bin with edge <= p, strict > left
// edge and > THRESHOLD filters. One packed fire-and-forget LDS atomic per
// valid element: u32 = (1<<20) | round(p*2048).
__device__ __forceinline__ void proc_f4(nf4 v, int i,
                                        const int* __restrict__ labels,
                                        unsigned int* s_pk, unsigned int* s_ac)
{
    int row  = i / 25;              // compiler magic-div (i < 12.5M)
    int col0 = (i - row * 25) * 4;  // float4 never crosses a row (100%4==0)
    int lbl  = labels[row];
    float pv[4] = {v.x, v.y, v.z, v.w};
    #pragma unroll
    for (int j = 0; j < 4; ++j) {
        float p = pv[j];
        int c = col0 + j;
        // searchsorted(bins, p, 'right') - 1: largest k with bins[k] <= p
        int k = (int)(p * 15.0f);
        if (k < NBINS && (float)(k + 1) * INV15 <= p)      ++k;
        else if (k > 0 && (float)k * INV15 > p)            --k;
        float left = (float)k * INV15;
        if (p > 0.01f && k < NBINS && p > left) {
            int seg = c * NBINS + k;
            unsigned int pk = (1u << 20) | (unsigned int)(p * SUMSCALE + 0.5f);
            atomicAdd(&s_pk[seg], pk);
            if (lbl == c) atomicAdd(&s_ac[seg], 1u);
        }
    }
}

// Kernel 0: zero the 18 KB global accumulator (workspace arrives poisoned).
__global__ __launch_bounds__(256) void calib_zero(unsigned int* __restrict__ g)
{
    int i = blockIdx.x * 256 + threadIdx.x;
    if (i < 3 * NSEG) g[i] = 0u;
}

// Kernel 1: grid-stride stream with 2-way MLP (two independent float4 loads
// per iteration, split-half indexing). Nontemporal loads: the 200 MB probas
// stream has zero reuse -> bypass L2 so the 18 KB accumulator stays hot.
// Flush: fire-and-forget global atomicAdd of the UNPACKED integer fields
// straight into gseg[3*NSEG] — no per-block partials, no mid kernel.
// ~3250 non-zero atomics/block x 2048 blocks = 6.7M no-return L2 atomics
// over 4500 addresses (~2048-deep per-address chains, pipelined in L2).
// Totals are u32-exact: cnt <= 500K, sumq <= 500K*2048 = 1.02e9 < 2^32.
__global__ __launch_bounds__(BLK) void calib_accum(
    const float* __restrict__ probas,
    const int*   __restrict__ labels,
    unsigned int* __restrict__ gseg,    // [3*NSEG]: cnt | sumq | acc
    int total4)
{
    __shared__ unsigned int s_pk[NSEG];   // packed: cnt<<20 | sum*2048
    __shared__ unsigned int s_ac[NSEG];   // label-match counts
    const int t = threadIdx.x;
    for (int i = t; i < NSEG; i += BLK) { s_pk[i] = 0u; s_ac[i] = 0u; }
    __syncthreads();

    const nf4* __restrict__ p4 = (const nf4*)probas;
    const int stride = gridDim.x * BLK;
    const int half4  = total4 >> 1;

    for (int i = blockIdx.x * BLK + t; i < half4; i += stride) {
        nf4 a = __builtin_nontemporal_load(&p4[i]);
        nf4 b = __builtin_nontemporal_load(&p4[i + half4]);
        proc_f4(a, i,         labels, s_pk, s_ac);
        proc_f4(b, i + half4, labels, s_pk, s_ac);
    }
    // odd total4 tail (not hit for N*C = 50M, kept for safety)
    if ((total4 & 1) && blockIdx.x == 0 && t == 0) {
        proc_f4(p4[total4 - 1], total4 - 1, labels, s_pk, s_ac);
    }
    __syncthreads();

    for (int s = t; s < NSEG; s += BLK) {
        unsigned int pk = s_pk[s];
        unsigned int ac = s_ac[s];
        if (pk) {
            atomicAdd(&gseg[s],        pk >> 20);      // count (exact)
            atomicAdd(&gseg[NSEG + s], pk & 0xFFFFFu); // quantized sum (exact int)
        }
        if (ac) atomicAdd(&gseg[2 * NSEG + s], ac);    // label matches (exact)
    }
}

// Kernel 2: read the 18 KB totals, divide, NaN for empty bins.
__global__ __launch_bounds__(256) void calib_fin(
    const unsigned int* __restrict__ gseg,
    float*              __restrict__ out)   // [confs(1500), accs(1500), n(1500)]
{
    int s = blockIdx.x * 256 + threadIdx.x;
    if (s >= NSEG) return;
    unsigned int cnt  = gseg[s];
    unsigned int sumq = gseg[NSEG + s];
    unsigned int acc  = gseg[2 * NSEG + s];
    float conf, accv;
    if (cnt > 0u) {
        float inv = 1.0f / (float)cnt;
        conf = (float)sumq * (1.0f / SUMSCALE) * inv;
        accv = (float)acc * inv;
    } else {
        conf = __int_as_float(0x7fc00000);
        accv = conf;
    }
    out[s]            = conf;
    out[NSEG + s]     = accv;
    out[2 * NSEG + s] = (float)cnt;
}

extern "C" void kernel_launch(void* const* d_in, const int* in_sizes, int n_in,
                              void* d_out, int out_size, void* d_ws, size_t ws_size,
                              hipStream_t stream) {
    const float* probas = (const float*)d_in[0];
    const int*   labels = (const int*)d_in[1];
    float* out = (float*)d_out;
    unsigned int* gseg = (unsigned int*)d_ws;   // 3*NSEG u32 = 18 KB

    int total  = in_sizes[0];      // N*C = 50,000,000 (divisible by 4; C=100)
    int total4 = total / 4;

    calib_zero <<<(3 * NSEG + 255) / 256, 256, 0, stream>>>(gseg);
    calib_accum<<<NBLK, BLK, 0, stream>>>(probas, labels, gseg, total4);
    calib_fin  <<<(NSEG + 255) / 256, 256, 0, stream>>>(gseg, out);
}

// Round 4
// 280.835 us; speedup vs baseline: 1.1253x; 1.1253x over previous
//
#include <hip/hip_runtime.h>

#define NBINS 15
#define NCLS  100
#define NSEG  (NBINS * NCLS)   // 1500
#define NGRP  64               // second-stage reduction groups
#define NBLK  512              // 2 blocks/CU at BLK=1024 -> 32 waves/CU
#define BLK   1024
#define SUMSCALE 2048.0f       // fixed-point scale for packed sum (20-bit field)
#define INV15 (1.0f / 15.0f)   // f32 edge arithmetic (round-2/5 proven vs np)

// native clang vector type — __builtin_nontemporal_load requires this
// (HIP_vector_type<float,4> is a class and is rejected).
typedef float nf4 __attribute__((ext_vector_type(4)));

// Per-float4 bin/accumulate. Exact searchsorted-right semantics:
// k = largest bin with edge <= p; strict > left edge and > THRESHOLD
// filters. One packed fire-and-forget LDS atomic per valid element:
// u32 = (1<<20) | round(p*2048). LDS atomics are block-local (32 banks,
// pipelined) — cheap. (Round-3 lesson: device-scope atomics to a tiny
// footprint serialize at the cross-XCD coherence point, +31 us. Never.)
__device__ __forceinline__ void proc_f4(nf4 v, int i,
                                        const int* __restrict__ labels,
                                        unsigned int* s_pk, unsigned int* s_ac)
{
    int row  = i / 25;              // compiler magic-div (i < 12.5M)
    int col0 = (i - row * 25) * 4;  // float4 never crosses a row (100%4==0)
    int lbl  = labels[row];
    float pv[4] = {v.x, v.y, v.z, v.w};
    #pragma unroll
    for (int j = 0; j < 4; ++j) {
        float p = pv[j];
        int c = col0 + j;
        // searchsorted(bins, p, 'right') - 1: largest k with bins[k] <= p
        int k = (int)(p * 15.0f);
        if (k < NBINS && (float)(k + 1) * INV15 <= p)      ++k;
        else if (k > 0 && (float)k * INV15 > p)            --k;
        float left = (float)k * INV15;
        if (p > 0.01f && k < NBINS && p > left) {
            int seg = c * NBINS + k;
            unsigned int pk = (1u << 20) | (unsigned int)(p * SUMSCALE + 0.5f);
            atomicAdd(&s_pk[seg], pk);
            if (lbl == c) atomicAdd(&s_ac[seg], 1u);
        }
    }
}

// Kernel 1: grid-stride stream, 2-way MLP (two independent float4 loads per
// iteration, split-half indexing), nontemporal (zero-reuse 200 MB stream,
// keep L2 for labels + partials). BLK=1024 x NBLK=512 keeps full occupancy
// (32 waves/CU) while aggregating 4x more elements per LDS flush:
// partU = 512 x 2*NSEG u32 = 6.1 MB (was 24.6 MB at 2048x256).
__global__ __launch_bounds__(BLK) void calib_accum(
    const float* __restrict__ probas,
    const int*   __restrict__ labels,
    unsigned int* __restrict__ partU,   // [nblk][2*NSEG]
    int total4)
{
    __shared__ unsigned int s_pk[NSEG];   // packed: cnt<<20 | sum*2048
    __shared__ unsigned int s_ac[NSEG];   // label-match counts
    const int t = threadIdx.x;
    for (int i = t; i < NSEG; i += BLK) { s_pk[i] = 0u; s_ac[i] = 0u; }
    __syncthreads();

    const nf4* __restrict__ p4 = (const nf4*)probas;
    const int stride = gridDim.x * BLK;
    const int half4  = total4 >> 1;

    for (int i = blockIdx.x * BLK + t; i < half4; i += stride) {
        nf4 a = __builtin_nontemporal_load(&p4[i]);
        nf4 b = __builtin_nontemporal_load(&p4[i + half4]);
        proc_f4(a, i,         labels, s_pk, s_ac);
        proc_f4(b, i + half4, labels, s_pk, s_ac);
    }
    // odd total4 tail (not hit for N*C = 50M, kept for safety)
    if ((total4 & 1) && blockIdx.x == 0 && t == 0) {
        proc_f4(p4[total4 - 1], total4 - 1, labels, s_pk, s_ac);
    }
    __syncthreads();

    unsigned int* dst = partU + (size_t)blockIdx.x * (2 * NSEG);
    for (int s = t; s < NSEG; s += BLK) {
        dst[s]        = s_pk[s];
        dst[NSEG + s] = s_ac[s];
    }
}

// Kernel 2: NGRP-way parallel partial reduction over blocks, coalesced on s.
// Accumulates in EXACT integers. Worst case per group (chunk = 512/64 = 8
// blocks x <=97657 elems/block): cnt < 2^20, sumq < 8 * 2^20 < 2^23 -> u32 safe.
__global__ __launch_bounds__(256) void calib_mid(
    const unsigned int* __restrict__ partU, int nblk, int chunk,
    unsigned int*       __restrict__ partB)   // [NGRP][3*NSEG]
{
    int t = blockIdx.x * 256 + threadIdx.x;
    if (t >= NGRP * NSEG) return;
    int g = t / NSEG;
    int s = t - g * NSEG;
    int b0 = g * chunk;
    int b1 = b0 + chunk; if (b1 > nblk) b1 = nblk;
    unsigned int cnt = 0u, sumq = 0u, acc = 0u;
    for (int b = b0; b < b1; ++b) {
        const unsigned int* src = partU + (size_t)b * (2 * NSEG);
        unsigned int pk = src[s];
        cnt  += pk >> 20;
        sumq += pk & 0xFFFFFu;
        acc  += src[NSEG + s];
    }
    unsigned int* dst = partB + (size_t)g * (3 * NSEG);
    dst[s]            = cnt;
    dst[NSEG + s]     = sumq;
    dst[2 * NSEG + s] = acc;
}

// Kernel 3: final integer sum over NGRP groups, then one float divide.
// Per-seg totals: cnt <= 500K, sumq <= 500K*2048 ~ 1.02e9 < 2^32 -> exact.
__global__ __launch_bounds__(256) void calib_fin(
    const unsigned int* __restrict__ partB,
    float*              __restrict__ out)   // [confs(1500), accs(1500), n(1500)]
{
    int s = blockIdx.x * 256 + threadIdx.x;
    if (s >= NSEG) return;
    unsigned int cnt = 0u, sumq = 0u, acc = 0u;
    #pragma unroll
    for (int g = 0; g < NGRP; ++g) {
        const unsigned int* src = partB + g * (3 * NSEG);
        cnt  += src[s];
        sumq += src[NSEG + s];
        acc  += src[2 * NSEG + s];
    }
    float conf, accv;
    if (cnt > 0u) {
        float inv = 1.0f / (float)cnt;
        conf = (float)sumq * (1.0f / SUMSCALE) * inv;
        accv = (float)acc * inv;
    } else {
        conf = __int_as_float(0x7fc00000);
        accv = conf;
    }
    out[s]            = conf;
    out[NSEG + s]     = accv;
    out[2 * NSEG + s] = (float)cnt;
}

extern "C" void kernel_launch(void* const* d_in, const int* in_sizes, int n_in,
                              void* d_out, int out_size, void* d_ws, size_t ws_size,
                              hipStream_t stream) {
    const float* probas = (const float*)d_in[0];
    const int*   labels = (const int*)d_in[1];
    float* out = (float*)d_out;
    unsigned int* ws = (unsigned int*)d_ws;

    int total  = in_sizes[0];      // N*C = 50,000,000 (divisible by 4; C=100)
    int total4 = total / 4;

    // workspace: partU [nblk][2*NSEG] u32, then partB [NGRP][3*NSEG] u32
    size_t ws_u32 = ws_size / sizeof(unsigned int);
    long long avail = (long long)ws_u32 - (long long)NGRP * 3 * NSEG;
    int nblk = (int)(avail / (2 * NSEG));
    if (nblk > NBLK) nblk = NBLK;
    if (nblk < 1) nblk = 1;

    unsigned int* partU = ws;
    unsigned int* partB = ws + (size_t)nblk * (2 * NSEG);

    calib_accum<<<nblk, BLK, 0, stream>>>(probas, labels, partU, total4);
    int chunk = (nblk + NGRP - 1) / NGRP;
    calib_mid<<<(NGRP * NSEG + 255) / 256, 256, 0, stream>>>(partU, nblk, chunk, partB);
    calib_fin<<<(NSEG + 255) / 256, 256, 0, stream>>>(partB, out);
}